// Round 4
// baseline (426.433 us; speedup 1.0000x reference)
//
#include <hip/hip_runtime.h>
#include <hip/hip_bf16.h>
#include <hip/hip_fp16.h>

// GAT, 2 layers. N=50000, F=128, H=4, C=32, E=1.6M (+N self-loops).
// R11: aggregate gathers are miss-latency bound (R8/R9/R10 postmortems:
// VALU halving neutral, MLP deepening negative). Fix the latency: h split
// into FOUR per-head quarters h[4][N][32]bf16 (3.2MB each < 4MB XCD-L2).
// Block parity b&3 selects the head; with round-robin b%8->XCD dispatch
// each XCD's L2 serves ONE quarter -> all gathers L2-hit after first
// touch. 1 wave = 4 nodes x 16 lanes; lane li gathers uint (feats 2li,
// 2li+1) = 64B line per edge-visit (same line traffic as R0, ~same VALU:
// per-u cost amortized over 4 edges, weight = scalar fp16 per-head array
// wq[4][E], no hi/lo select). col/w loads NT, out stores NT (don't evict
// the resident quarter). Inner loop: 8-edge chunks + scalar tail.
// GEMM: split-bf16 MFMA (R5), epilogue writes quarter layout. CSR: R3.

#define FDIM 128
#define NHEAD 4
#define NB 512          // dst buckets for CSR build

typedef __attribute__((ext_vector_type(16))) float f32x16;
typedef __attribute__((ext_vector_type(8)))  short s16x8;

__device__ inline unsigned short f2bf(float f) {
    union { float f; unsigned u; } v; v.f = f;
    unsigned r = v.u + 0x7fff + ((v.u >> 16) & 1);   // RNE
    return (unsigned short)(r >> 16);
}
__device__ inline float2 bf2f(unsigned v) {
    union { unsigned u; float f; } a, b;
    a.u = v << 16;            // low half  = feature 2c
    b.u = v & 0xffff0000u;    // high half = feature 2c+1
    return make_float2(a.f, b.f);
}
__device__ inline void splitbf(float f, short* hi, short* lo) {
    unsigned u = __float_as_uint(f);
    float rem = f - __uint_as_float(u & 0xffff0000u);
    *hi = (short)(u >> 16);
    *lo = (short)(__float_as_uint(rem) >> 16);
}

// ---- fused: prep W1/W2 (transpose+split+swizzle) + bucket histogram ------
__global__ __launch_bounds__(256) void prep_hist(const float* __restrict__ W1,
                                                 short* __restrict__ B1hi,
                                                 short* __restrict__ B1lo,
                                                 const float* __restrict__ W2,
                                                 short* __restrict__ B2hi,
                                                 short* __restrict__ B2lo,
                                                 const int* __restrict__ dst, int E,
                                                 unsigned long long magic,
                                                 int* __restrict__ bcnt) {
    __shared__ int sh[NB];
    const int t = threadIdx.x;
    const int b = blockIdx.x;
    if (b < 128) {
        const float* W = (b < 64) ? W1 : W2;
        short* Bhi = (b < 64) ? B1hi : B2hi;
        short* Blo = (b < 64) ? B1lo : B2lo;
        int e = (b & 63) * 256 + t;   // e = k*128 + n
        int k = e >> 7, n = e & 127;
        short hi, lo;
        splitbf(W[e], &hi, &lo);
        int idx = n * 128 + (((k >> 3) ^ (n & 15)) << 3) + (k & 7);
        Bhi[idx] = hi;
        Blo[idx] = lo;
        return;
    }
    for (int i = t; i < NB; i += 256) sh[i] = 0;
    __syncthreads();
    const int stride = (gridDim.x - 128) * 256;
    for (int i = (b - 128) * 256 + t; i < E; i += stride) {
        int bk = (int)(((unsigned long long)(unsigned)dst[i] * magic) >> 40);
        atomicAdd(&sh[bk], 1);
    }
    __syncthreads();
    for (int i = t; i < NB; i += 256)
        if (sh[i]) atomicAdd(&bcnt[i], sh[i]);
}

// ---- MFMA GEMM: H[4][M][32](bf16) = A[M][128](f32) @ W; fused a_s/a_d ----
__global__ __launch_bounds__(256) void gemm_mfma(const float* __restrict__ A,
                                                 const short* __restrict__ Bghi,
                                                 const short* __restrict__ Bglo,
                                                 unsigned short* __restrict__ H,
                                                 const float* __restrict__ att_s,
                                                 const float* __restrict__ att_d,
                                                 float* __restrict__ a_s,
                                                 float* __restrict__ a_d, int M) {
    __shared__ short Bsm[2][16384];   // 64 KB: [hi/lo][n*128 + k']
    __shared__ float attsm[256];      // att_s[128], att_d[128]
    const int t = threadIdx.x;
    const int bm = blockIdx.x * 64;

    if (t < 128) attsm[t] = att_s[t];
    else         attsm[t] = att_d[t - 128];

    {   // stage B (pre-swizzled; verbatim 32KB+32KB copy)
        const uint4* ghi = (const uint4*)Bghi;
        const uint4* glo = (const uint4*)Bglo;
        uint4* shi = (uint4*)&Bsm[0][0];
        uint4* slo = (uint4*)&Bsm[1][0];
        #pragma unroll
        for (int i = 0; i < 8; i++) {
            shi[t + i * 256] = ghi[t + i * 256];
            slo[t + i * 256] = glo[t + i * 256];
        }
    }

    const int lane = t & 63;
    const int w = t >> 6;
    const int wr = w >> 1, wc = w & 1;     // wave tile: rows wr*32, cols wc*32
    const int m  = lane & 31, h2 = lane >> 5;
    const int grow = bm + wr * 32 + m;

    // A fragments: 8 k-chunks of 16; lane holds k = 16c + 8*h2 + j (j=0..7)
    s16x8 ahi[8], alo[8];
    {
        const bool ok = grow < M;
        const float* ap = A + (size_t)grow * 128 + 8 * h2;
        #pragma unroll
        for (int c = 0; c < 8; c++) {
            float ff[8];
            if (ok) {
                float4 f0 = *(const float4*)(ap + c * 16);
                float4 f1 = *(const float4*)(ap + c * 16 + 4);
                ff[0]=f0.x; ff[1]=f0.y; ff[2]=f0.z; ff[3]=f0.w;
                ff[4]=f1.x; ff[5]=f1.y; ff[6]=f1.z; ff[7]=f1.w;
            } else {
                #pragma unroll
                for (int j = 0; j < 8; j++) ff[j] = 0.f;
            }
            #pragma unroll
            for (int j = 0; j < 8; j++) {
                short hi, lo;
                splitbf(ff[j], &hi, &lo);
                ahi[c][j] = hi;
                alo[c][j] = lo;
            }
        }
    }
    __syncthreads();

    f32x16 acc[2];
    #pragma unroll
    for (int i = 0; i < 16; i++) { acc[0][i] = 0.f; acc[1][i] = 0.f; }

    #pragma unroll
    for (int ni = 0; ni < 2; ni++) {
        const int n = ni * 64 + wc * 32 + m;     // B col for this lane
        const int nbase = n * 128;
        #pragma unroll
        for (int c = 0; c < 8; c++) {
            int chunk8 = 2 * c + h2;
            int koff = ((chunk8 ^ (n & 15)) << 3);
            s16x8 bhi = *(const s16x8*)&Bsm[0][nbase + koff];
            s16x8 blo = *(const s16x8*)&Bsm[1][nbase + koff];
            acc[ni] = __builtin_amdgcn_mfma_f32_32x32x16_bf16(ahi[c], bhi, acc[ni], 0, 0, 0);
            acc[ni] = __builtin_amdgcn_mfma_f32_32x32x16_bf16(alo[c], bhi, acc[ni], 0, 0, 0);
            acc[ni] = __builtin_amdgcn_mfma_f32_32x32x16_bf16(ahi[c], blo, acc[ni], 0, 0, 0);
        }
    }

    __syncthreads();   // all waves done reading Bsm; reuse as htile
    unsigned short* htile = (unsigned short*)&Bsm[0][0];   // [64][128] bf16
    #pragma unroll
    for (int ni = 0; ni < 2; ni++) {
        const int colg = ni * 64 + wc * 32 + m;
        #pragma unroll
        for (int r = 0; r < 16; r++) {
            int row = wr * 32 + (r & 3) + 8 * (r >> 2) + 4 * h2;  // C/D m74/m101
            htile[row * 128 + colg] = (short)f2bf(acc[ni][r]);
        }
    }
    __syncthreads();

    // copy h tile out (quarter layout H[q][M][32]) + logits: thread = (r,q)
    {
        const int r = t >> 2, q = t & 3;
        const int growr = bm + r;
        if (growr < M) {
            uint4 v0 = *(uint4*)&htile[r * 128 + q * 32];
            uint4 v1 = *(uint4*)&htile[r * 128 + q * 32 + 8];
            uint4 v2 = *(uint4*)&htile[r * 128 + q * 32 + 16];
            uint4 v3 = *(uint4*)&htile[r * 128 + q * 32 + 24];
            uint4* hg = (uint4*)(H + ((size_t)q * M + growr) * 32);
            hg[0] = v0; hg[1] = v1; hg[2] = v2; hg[3] = v3;
            unsigned uu[16] = {v0.x, v0.y, v0.z, v0.w, v1.x, v1.y, v1.z, v1.w,
                               v2.x, v2.y, v2.z, v2.w, v3.x, v3.y, v3.z, v3.w};
            float ps = 0.f, pd = 0.f;
            #pragma unroll
            for (int i = 0; i < 16; i++) {
                float2 f = bf2f(uu[i]);
                ps += f.x * attsm[q * 32 + 2 * i]       + f.y * attsm[q * 32 + 2 * i + 1];
                pd += f.x * attsm[128 + q * 32 + 2 * i] + f.y * attsm[128 + q * 32 + 2 * i + 1];
            }
            a_s[growr * NHEAD + q] = ps;
            a_d[growr * NHEAD + q] = pd;
        }
    }
}

// ------------------------------ CSR build ---------------------------------
__global__ __launch_bounds__(256) void bucket_scan(const int* __restrict__ bcnt,
                                                   int* __restrict__ bbase,
                                                   int* __restrict__ bcursor,
                                                   int* __restrict__ row_ptr,
                                                   int N, int E) {
    __shared__ int wsum[4];
    const int t = threadIdx.x, lane = t & 63, wid = t >> 6;
    int v0 = bcnt[2 * t], v1 = bcnt[2 * t + 1];
    int s = v0 + v1, incl = s;
    #pragma unroll
    for (int o = 1; o < 64; o <<= 1) {
        int u = __shfl_up(incl, o, 64);
        if (lane >= o) incl += u;
    }
    if (lane == 63) wsum[wid] = incl;
    __syncthreads();
    if (t == 0) {
        int a = 0;
        #pragma unroll
        for (int i = 0; i < 4; i++) { int x = wsum[i]; wsum[i] = a; a += x; }
    }
    __syncthreads();
    int excl = wsum[wid] + incl - s;
    bbase[2 * t] = excl;          bcursor[2 * t] = excl;
    bbase[2 * t + 1] = excl + v0; bcursor[2 * t + 1] = excl + v0;
    if (t == 0) { bbase[NB] = E; row_ptr[N] = E; }
}

__global__ __launch_bounds__(256) void partition(const int* __restrict__ src,
                                                 const int* __restrict__ dst, int E,
                                                 unsigned long long magic,
                                                 int* __restrict__ bcursor,
                                                 int2* __restrict__ ebuf) {
    __shared__ int shc[NB];    // per-bucket count in this block
    __shared__ int shb[NB];    // reserved global base
    __shared__ int shcur[NB];  // local cursor
    const int t = threadIdx.x;
    for (int i = t; i < NB; i += 256) shc[i] = 0;
    __syncthreads();
    const int e0 = blockIdx.x * 4096;
    int myb[16], mys[16], myd[16];
    #pragma unroll
    for (int u = 0; u < 16; u++) {
        int i = e0 + u * 256 + t;
        if (i < E) {
            mys[u] = src[i];
            myd[u] = dst[i];
            int b = (int)(((unsigned long long)(unsigned)myd[u] * magic) >> 40);
            myb[u] = b;
            atomicAdd(&shc[b], 1);
        } else myb[u] = -1;
    }
    __syncthreads();
    for (int i = t; i < NB; i += 256) {
        int c = shc[i];
        shcur[i] = 0;
        if (c) shb[i] = atomicAdd(&bcursor[i], c);
    }
    __syncthreads();
    #pragma unroll
    for (int u = 0; u < 16; u++) {
        if (myb[u] >= 0) {
            int o = atomicAdd(&shcur[myb[u]], 1);
            ebuf[shb[myb[u]] + o] = make_int2(mys[u], myd[u]);
        }
    }
}

__global__ __launch_bounds__(256) void build_bucket(const int2* __restrict__ ebuf,
                                                    const int* __restrict__ bbase,
                                                    int npb, int N,
                                                    int* __restrict__ row_ptr,
                                                    int* __restrict__ col,
                                                    int* __restrict__ edst) {
    __shared__ int degl[256];
    __shared__ int curl[256];
    const int b = blockIdx.x;
    const int t = threadIdx.x, lane = t & 63, wid = t >> 6;
    const int base = bbase[b];
    const int cnt = bbase[b + 1] - base;
    const int node0 = b * npb;
    for (int i = t; i < npb; i += 256) degl[i] = 0;
    __syncthreads();
    for (int i = t; i < cnt; i += 256) {
        int d = ebuf[base + i].y;
        atomicAdd(&degl[d - node0], 1);
    }
    __syncthreads();
    if (wid == 0) {
        int run = 0;
        for (int c = 0; c * 64 < npb; c++) {
            int idx = c * 64 + lane;
            int v = (idx < npb) ? degl[idx] : 0;
            int incl = v;
            #pragma unroll
            for (int o = 1; o < 64; o <<= 1) {
                int u = __shfl_up(incl, o, 64);
                if (lane >= o) incl += u;
            }
            int excl = incl - v + run;
            if (idx < npb) {
                curl[idx] = excl;
                int node = node0 + idx;
                if (node < N) row_ptr[node] = base + excl;
            }
            run += __shfl(incl, 63, 64);
        }
    }
    __syncthreads();
    for (int i = t; i < cnt; i += 256) {
        int2 ed = ebuf[base + i];
        int p = atomicAdd(&curl[ed.y - node0], 1);
        col[base + p] = ed.x;
        edst[base + p] = ed.y;
    }
}

// ---- per-(edge,head) softmax weights, fp16, one array per head -----------
__global__ __launch_bounds__(256) void edge_w(const int* __restrict__ col,
                                              const int* __restrict__ edst,
                                              const float4* __restrict__ as4,
                                              const float4* __restrict__ ad4,
                                              int E,
                                              unsigned short* __restrict__ q0,
                                              unsigned short* __restrict__ q1,
                                              unsigned short* __restrict__ q2,
                                              unsigned short* __restrict__ q3) {
    int i = blockIdx.x * 256 + threadIdx.x;
    if (i >= E) return;
    float4 a = as4[col[i]];
    float4 b = ad4[edst[i]];
    float ex = a.x + b.x, ey = a.y + b.y, ez = a.z + b.z, ew = a.w + b.w;
    ex = fmaxf(ex, 0.2f * ex); ey = fmaxf(ey, 0.2f * ey);
    ez = fmaxf(ez, 0.2f * ez); ew = fmaxf(ew, 0.2f * ew);
    __half hx = __float2half(__expf(ex));
    __half hy = __float2half(__expf(ey));
    __half hz = __float2half(__expf(ez));
    __half hw = __float2half(__expf(ew));
    q0[i] = *(unsigned short*)&hx;
    q1[i] = *(unsigned short*)&hy;
    q2[i] = *(unsigned short*)&hz;
    q3[i] = *(unsigned short*)&hw;
}

// ------------- gather aggregation: softmax-weighted sum per dst ------------
// R11: block = 1 wave = 4 nodes x 16 lanes; parity p=b&3 selects head and
// its 3.2MB h quarter (L2-resident per XCD under round-robin dispatch).
// lane li gathers uint = feats 2li,2li+1 of h[p][node][32]. Weight =
// scalar fp16 from wq[p][E] (NT load). col NT loads; out NT stores.
__global__ __launch_bounds__(64) void aggregate(const unsigned short* __restrict__ hq,
                                                const unsigned short* __restrict__ wq,
                                                const float* __restrict__ a_s,
                                                const float* __restrict__ a_d,
                                                const int* __restrict__ row_ptr,
                                                const int* __restrict__ col,
                                                const float* __restrict__ bias,
                                                float* __restrict__ out,
                                                float* __restrict__ out2,
                                                int n, int E, int do_relu) {
    const int b = blockIdx.x;
    const int p = b & 3;                    // head (parity)
    const unsigned* __restrict__ hp =
        (const unsigned*)(hq + (size_t)p * n * 32);        // uint = 2 feats
    const unsigned short* __restrict__ wp = wq + (size_t)p * E;
    const int t = threadIdx.x;
    const int g  = t >> 4;                  // node within quad
    const int li = t & 15;                  // feature pair: feats 2li,2li+1
    const int node = (b >> 2) * 4 + g;
    const bool valid = node < n;
    const int nd = valid ? node : 0;

    // self loop
    float e = a_s[nd * NHEAD + p] + a_d[nd * NHEAD + p];
    e = fmaxf(e, 0.2f * e);
    float den = __expf(e);
    float num0, num1;
    {
        float2 hv = bf2f(hp[(size_t)nd * 16 + li]);
        num0 = den * hv.x;
        num1 = den * hv.y;
    }

    const int beg = row_ptr[nd];
    const int end = valid ? row_ptr[nd + 1] : beg;
    int j = beg;
    for (; j + 8 <= end; j += 8) {
        int s[8];
        #pragma unroll
        for (int u = 0; u < 8; u++) s[u] = __builtin_nontemporal_load(&col[j + u]);
        unsigned v[8];
        #pragma unroll
        for (int u = 0; u < 8; u++) v[u] = hp[(size_t)s[u] * 16 + li];
        unsigned short hw[8];
        #pragma unroll
        for (int u = 0; u < 8; u++) hw[u] = __builtin_nontemporal_load(&wp[j + u]);
        #pragma unroll
        for (int u = 0; u < 8; u++) {
            float wgt = __half2float(*(const __half*)&hw[u]);
            den += wgt;
            float2 f = bf2f(v[u]);
            num0 += wgt * f.x;
            num1 += wgt * f.y;
        }
    }
    for (; j < end; j++) {
        int s = col[j];
        unsigned short hw = wp[j];
        float wgt = __half2float(*(const __half*)&hw);
        den += wgt;
        float2 f = bf2f(hp[(size_t)s * 16 + li]);
        num0 += wgt * f.x;
        num1 += wgt * f.y;
    }

    if (valid) {
        float2 bv = ((const float2*)bias)[p * 16 + li];
        float rd = 1.0f / den;
        float o0 = num0 * rd + bv.x;
        float o1 = num1 * rd + bv.y;
        if (do_relu) { o0 = fmaxf(o0, 0.f); o1 = fmaxf(o1, 0.f); }
        float2 o = make_float2(o0, o1);
        double dv;
        __builtin_memcpy(&dv, &o, 8);
        __builtin_nontemporal_store(dv, (double*)((float2*)out + (size_t)node * 64 + p * 16 + li));
        if (out2)
            __builtin_nontemporal_store(dv, (double*)((float2*)out2 + (size_t)node * 64 + p * 16 + li));
    }
}

// ------------------------------- launcher ----------------------------------
extern "C" void kernel_launch(void* const* d_in, const int* in_sizes, int n_in,
                              void* d_out, int out_size, void* d_ws, size_t ws_size,
                              hipStream_t stream) {
    const float* x        = (const float*)d_in[0];
    const int*   edge     = (const int*)d_in[1];
    const float* W1       = (const float*)d_in[2];
    const float* att_s1   = (const float*)d_in[3];
    const float* att_d1   = (const float*)d_in[4];
    const float* b1       = (const float*)d_in[5];
    const float* W2       = (const float*)d_in[6];
    const float* att_s2   = (const float*)d_in[7];
    const float* att_d2   = (const float*)d_in[8];
    const float* b2       = (const float*)d_in[9];
    float* out = (float*)d_out;

    const int N = in_sizes[0] / FDIM;         // 50000
    const int E = in_sizes[1] / 2;            // 1600000
    const int* src = edge;
    const int* dst = edge + E;

    const int npb = (N + NB - 1) / NB;        // 98
    const unsigned long long magic = ((1ull << 40) / (unsigned long long)npb) + 1;

    char* w = (char*)d_ws;
    size_t off = 0;
    auto alloc = [&](size_t bytes) { void* p = w + off; off = (off + bytes + 255) & ~(size_t)255; return p; };
    int*   row_ptr = (int*)alloc((size_t)(N + 1) * 4);
    int*   col     = (int*)alloc((size_t)E * 4);
    int*   edst    = (int*)alloc((size_t)E * 4);
    unsigned short* wqa = (unsigned short*)alloc((size_t)4 * E * 2);  // [4][E] fp16
    int*   bcnt    = (int*)alloc((size_t)NB * 4);
    int*   bbase   = (int*)alloc((size_t)(NB + 1) * 4);
    int*   bcursor = (int*)alloc((size_t)NB * 4);
    unsigned short* h = (unsigned short*)alloc((size_t)4 * N * 32 * 2); // [4][N][32] bf16
    float* hx      = (float*)alloc((size_t)N * FDIM * 4);   // layer-1 out; ebuf alias
    float* as1     = (float*)alloc((size_t)N * NHEAD * 4);
    float* ad1     = (float*)alloc((size_t)N * NHEAD * 4);
    float* as2     = (float*)alloc((size_t)N * NHEAD * 4);
    float* ad2     = (float*)alloc((size_t)N * NHEAD * 4);
    short* Bg1hi   = (short*)alloc((size_t)128 * 128 * 2);
    short* Bg1lo   = (short*)alloc((size_t)128 * 128 * 2);
    short* Bg2hi   = (short*)alloc((size_t)128 * 128 * 2);
    short* Bg2lo   = (short*)alloc((size_t)128 * 128 * 2);
    int2*  ebuf    = (int2*)hx;   // dead before aggregate-1 writes hx
    (void)ws_size;

    // ---- fused weight-prep + bucket histogram ----
    hipMemsetAsync(bcnt, 0, (size_t)NB * 4, stream);
    prep_hist<<<128 + 1024, 256, 0, stream>>>(W1, Bg1hi, Bg1lo, W2, Bg2hi, Bg2lo,
                                              dst, E, magic, bcnt);
    bucket_scan<<<1, 256, 0, stream>>>(bcnt, bbase, bcursor, row_ptr, N, E);
    partition<<<(E + 4095) / 4096, 256, 0, stream>>>(src, dst, E, magic, bcursor, ebuf);
    build_bucket<<<NB, 256, 0, stream>>>(ebuf, bbase, npb, N, row_ptr, col, edst);

    const int gblocks = (N + 63) / 64;
    const int eb = (E + 255) / 256;
    const int ablocks = ((N + 3) / 4) * 4;    // node quads x 4 head parities

    // ---- layer 1 ----
    gemm_mfma<<<gblocks, 256, 0, stream>>>(x, Bg1hi, Bg1lo, h,
                                           att_s1, att_d1, as1, ad1, N);
    edge_w<<<eb, 256, 0, stream>>>(col, edst, (const float4*)as1, (const float4*)ad1,
                                   E, wqa, wqa + (size_t)E, wqa + (size_t)2 * E,
                                   wqa + (size_t)3 * E);
    aggregate<<<ablocks, 64, 0, stream>>>(h, wqa, as1, ad1, row_ptr, col, b1,
                                          hx, nullptr, N, E, 1);

    // ---- layer 2 ----
    gemm_mfma<<<gblocks, 256, 0, stream>>>(hx, Bg2hi, Bg2lo, h,
                                           att_s2, att_d2, as2, ad2, N);
    edge_w<<<eb, 256, 0, stream>>>(col, edst, (const float4*)as2, (const float4*)ad2,
                                   E, wqa, wqa + (size_t)E, wqa + (size_t)2 * E,
                                   wqa + (size_t)3 * E);
    aggregate<<<ablocks, 64, 0, stream>>>(h, wqa, as2, ad2, row_ptr, col, b2,
                                          out, out + (size_t)N * FDIM, N, E, 0);
}

// Round 5
// 351.681 us; speedup vs baseline: 1.2126x; 1.2126x over previous
//
#include <hip/hip_runtime.h>
#include <hip/hip_bf16.h>
#include <hip/hip_fp16.h>

// GAT, 2 layers. N=50000, F=128, H=4, C=32, E=1.6M (+N self-loops).
// R11: h split into per-head quarters h[4][N][32]bf16 (3.2MB < 4MB XCD-L2);
// block parity b&3 selects head; round-robin b%8->XCD gives each XCD one
// resident quarter. 1 wave = 4 nodes x 16 lanes, lane li gathers uint
// (feats 2li,2li+1); weight = scalar fp16 wq[4][E].
// R12: REMOVE all nontemporal hints (R11 postmortem: NT loads on col/w
// bypass L1/L2 allocation -> every 64B line of col re-fetched from LLC
// 16x, adding an LLC round trip to the dependent col->gather chain; VALU
// 56->36%, dur 64->106. Plain loads restore L1/L2 hits on the streams).
// GEMM: split-bf16 MFMA (R5), epilogue writes quarter layout. CSR: R3.

#define FDIM 128
#define NHEAD 4
#define NB 512          // dst buckets for CSR build

typedef __attribute__((ext_vector_type(16))) float f32x16;
typedef __attribute__((ext_vector_type(8)))  short s16x8;

__device__ inline unsigned short f2bf(float f) {
    union { float f; unsigned u; } v; v.f = f;
    unsigned r = v.u + 0x7fff + ((v.u >> 16) & 1);   // RNE
    return (unsigned short)(r >> 16);
}
__device__ inline float2 bf2f(unsigned v) {
    union { unsigned u; float f; } a, b;
    a.u = v << 16;            // low half  = feature 2c
    b.u = v & 0xffff0000u;    // high half = feature 2c+1
    return make_float2(a.f, b.f);
}
__device__ inline void splitbf(float f, short* hi, short* lo) {
    unsigned u = __float_as_uint(f);
    float rem = f - __uint_as_float(u & 0xffff0000u);
    *hi = (short)(u >> 16);
    *lo = (short)(__float_as_uint(rem) >> 16);
}

// ---- fused: prep W1/W2 (transpose+split+swizzle) + bucket histogram ------
__global__ __launch_bounds__(256) void prep_hist(const float* __restrict__ W1,
                                                 short* __restrict__ B1hi,
                                                 short* __restrict__ B1lo,
                                                 const float* __restrict__ W2,
                                                 short* __restrict__ B2hi,
                                                 short* __restrict__ B2lo,
                                                 const int* __restrict__ dst, int E,
                                                 unsigned long long magic,
                                                 int* __restrict__ bcnt) {
    __shared__ int sh[NB];
    const int t = threadIdx.x;
    const int b = blockIdx.x;
    if (b < 128) {
        const float* W = (b < 64) ? W1 : W2;
        short* Bhi = (b < 64) ? B1hi : B2hi;
        short* Blo = (b < 64) ? B1lo : B2lo;
        int e = (b & 63) * 256 + t;   // e = k*128 + n
        int k = e >> 7, n = e & 127;
        short hi, lo;
        splitbf(W[e], &hi, &lo);
        int idx = n * 128 + (((k >> 3) ^ (n & 15)) << 3) + (k & 7);
        Bhi[idx] = hi;
        Blo[idx] = lo;
        return;
    }
    for (int i = t; i < NB; i += 256) sh[i] = 0;
    __syncthreads();
    const int stride = (gridDim.x - 128) * 256;
    for (int i = (b - 128) * 256 + t; i < E; i += stride) {
        int bk = (int)(((unsigned long long)(unsigned)dst[i] * magic) >> 40);
        atomicAdd(&sh[bk], 1);
    }
    __syncthreads();
    for (int i = t; i < NB; i += 256)
        if (sh[i]) atomicAdd(&bcnt[i], sh[i]);
}

// ---- MFMA GEMM: H[4][M][32](bf16) = A[M][128](f32) @ W; fused a_s/a_d ----
__global__ __launch_bounds__(256) void gemm_mfma(const float* __restrict__ A,
                                                 const short* __restrict__ Bghi,
                                                 const short* __restrict__ Bglo,
                                                 unsigned short* __restrict__ H,
                                                 const float* __restrict__ att_s,
                                                 const float* __restrict__ att_d,
                                                 float* __restrict__ a_s,
                                                 float* __restrict__ a_d, int M) {
    __shared__ short Bsm[2][16384];   // 64 KB: [hi/lo][n*128 + k']
    __shared__ float attsm[256];      // att_s[128], att_d[128]
    const int t = threadIdx.x;
    const int bm = blockIdx.x * 64;

    if (t < 128) attsm[t] = att_s[t];
    else         attsm[t] = att_d[t - 128];

    {   // stage B (pre-swizzled; verbatim 32KB+32KB copy)
        const uint4* ghi = (const uint4*)Bghi;
        const uint4* glo = (const uint4*)Bglo;
        uint4* shi = (uint4*)&Bsm[0][0];
        uint4* slo = (uint4*)&Bsm[1][0];
        #pragma unroll
        for (int i = 0; i < 8; i++) {
            shi[t + i * 256] = ghi[t + i * 256];
            slo[t + i * 256] = glo[t + i * 256];
        }
    }

    const int lane = t & 63;
    const int w = t >> 6;
    const int wr = w >> 1, wc = w & 1;     // wave tile: rows wr*32, cols wc*32
    const int m  = lane & 31, h2 = lane >> 5;
    const int grow = bm + wr * 32 + m;

    // A fragments: 8 k-chunks of 16; lane holds k = 16c + 8*h2 + j (j=0..7)
    s16x8 ahi[8], alo[8];
    {
        const bool ok = grow < M;
        const float* ap = A + (size_t)grow * 128 + 8 * h2;
        #pragma unroll
        for (int c = 0; c < 8; c++) {
            float ff[8];
            if (ok) {
                float4 f0 = *(const float4*)(ap + c * 16);
                float4 f1 = *(const float4*)(ap + c * 16 + 4);
                ff[0]=f0.x; ff[1]=f0.y; ff[2]=f0.z; ff[3]=f0.w;
                ff[4]=f1.x; ff[5]=f1.y; ff[6]=f1.z; ff[7]=f1.w;
            } else {
                #pragma unroll
                for (int j = 0; j < 8; j++) ff[j] = 0.f;
            }
            #pragma unroll
            for (int j = 0; j < 8; j++) {
                short hi, lo;
                splitbf(ff[j], &hi, &lo);
                ahi[c][j] = hi;
                alo[c][j] = lo;
            }
        }
    }
    __syncthreads();

    f32x16 acc[2];
    #pragma unroll
    for (int i = 0; i < 16; i++) { acc[0][i] = 0.f; acc[1][i] = 0.f; }

    #pragma unroll
    for (int ni = 0; ni < 2; ni++) {
        const int n = ni * 64 + wc * 32 + m;     // B col for this lane
        const int nbase = n * 128;
        #pragma unroll
        for (int c = 0; c < 8; c++) {
            int chunk8 = 2 * c + h2;
            int koff = ((chunk8 ^ (n & 15)) << 3);
            s16x8 bhi = *(const s16x8*)&Bsm[0][nbase + koff];
            s16x8 blo = *(const s16x8*)&Bsm[1][nbase + koff];
            acc[ni] = __builtin_amdgcn_mfma_f32_32x32x16_bf16(ahi[c], bhi, acc[ni], 0, 0, 0);
            acc[ni] = __builtin_amdgcn_mfma_f32_32x32x16_bf16(alo[c], bhi, acc[ni], 0, 0, 0);
            acc[ni] = __builtin_amdgcn_mfma_f32_32x32x16_bf16(ahi[c], blo, acc[ni], 0, 0, 0);
        }
    }

    __syncthreads();   // all waves done reading Bsm; reuse as htile
    unsigned short* htile = (unsigned short*)&Bsm[0][0];   // [64][128] bf16
    #pragma unroll
    for (int ni = 0; ni < 2; ni++) {
        const int colg = ni * 64 + wc * 32 + m;
        #pragma unroll
        for (int r = 0; r < 16; r++) {
            int row = wr * 32 + (r & 3) + 8 * (r >> 2) + 4 * h2;  // C/D m74/m101
            htile[row * 128 + colg] = (short)f2bf(acc[ni][r]);
        }
    }
    __syncthreads();

    // copy h tile out (quarter layout H[q][M][32]) + logits: thread = (r,q)
    {
        const int r = t >> 2, q = t & 3;
        const int growr = bm + r;
        if (growr < M) {
            uint4 v0 = *(uint4*)&htile[r * 128 + q * 32];
            uint4 v1 = *(uint4*)&htile[r * 128 + q * 32 + 8];
            uint4 v2 = *(uint4*)&htile[r * 128 + q * 32 + 16];
            uint4 v3 = *(uint4*)&htile[r * 128 + q * 32 + 24];
            uint4* hg = (uint4*)(H + ((size_t)q * M + growr) * 32);
            hg[0] = v0; hg[1] = v1; hg[2] = v2; hg[3] = v3;
            unsigned uu[16] = {v0.x, v0.y, v0.z, v0.w, v1.x, v1.y, v1.z, v1.w,
                               v2.x, v2.y, v2.z, v2.w, v3.x, v3.y, v3.z, v3.w};
            float ps = 0.f, pd = 0.f;
            #pragma unroll
            for (int i = 0; i < 16; i++) {
                float2 f = bf2f(uu[i]);
                ps += f.x * attsm[q * 32 + 2 * i]       + f.y * attsm[q * 32 + 2 * i + 1];
                pd += f.x * attsm[128 + q * 32 + 2 * i] + f.y * attsm[128 + q * 32 + 2 * i + 1];
            }
            a_s[growr * NHEAD + q] = ps;
            a_d[growr * NHEAD + q] = pd;
        }
    }
}

// ------------------------------ CSR build ---------------------------------
__global__ __launch_bounds__(256) void bucket_scan(const int* __restrict__ bcnt,
                                                   int* __restrict__ bbase,
                                                   int* __restrict__ bcursor,
                                                   int* __restrict__ row_ptr,
                                                   int N, int E) {
    __shared__ int wsum[4];
    const int t = threadIdx.x, lane = t & 63, wid = t >> 6;
    int v0 = bcnt[2 * t], v1 = bcnt[2 * t + 1];
    int s = v0 + v1, incl = s;
    #pragma unroll
    for (int o = 1; o < 64; o <<= 1) {
        int u = __shfl_up(incl, o, 64);
        if (lane >= o) incl += u;
    }
    if (lane == 63) wsum[wid] = incl;
    __syncthreads();
    if (t == 0) {
        int a = 0;
        #pragma unroll
        for (int i = 0; i < 4; i++) { int x = wsum[i]; wsum[i] = a; a += x; }
    }
    __syncthreads();
    int excl = wsum[wid] + incl - s;
    bbase[2 * t] = excl;          bcursor[2 * t] = excl;
    bbase[2 * t + 1] = excl + v0; bcursor[2 * t + 1] = excl + v0;
    if (t == 0) { bbase[NB] = E; row_ptr[N] = E; }
}

__global__ __launch_bounds__(256) void partition(const int* __restrict__ src,
                                                 const int* __restrict__ dst, int E,
                                                 unsigned long long magic,
                                                 int* __restrict__ bcursor,
                                                 int2* __restrict__ ebuf) {
    __shared__ int shc[NB];    // per-bucket count in this block
    __shared__ int shb[NB];    // reserved global base
    __shared__ int shcur[NB];  // local cursor
    const int t = threadIdx.x;
    for (int i = t; i < NB; i += 256) shc[i] = 0;
    __syncthreads();
    const int e0 = blockIdx.x * 4096;
    int myb[16], mys[16], myd[16];
    #pragma unroll
    for (int u = 0; u < 16; u++) {
        int i = e0 + u * 256 + t;
        if (i < E) {
            mys[u] = src[i];
            myd[u] = dst[i];
            int b = (int)(((unsigned long long)(unsigned)myd[u] * magic) >> 40);
            myb[u] = b;
            atomicAdd(&shc[b], 1);
        } else myb[u] = -1;
    }
    __syncthreads();
    for (int i = t; i < NB; i += 256) {
        int c = shc[i];
        shcur[i] = 0;
        if (c) shb[i] = atomicAdd(&bcursor[i], c);
    }
    __syncthreads();
    #pragma unroll
    for (int u = 0; u < 16; u++) {
        if (myb[u] >= 0) {
            int o = atomicAdd(&shcur[myb[u]], 1);
            ebuf[shb[myb[u]] + o] = make_int2(mys[u], myd[u]);
        }
    }
}

__global__ __launch_bounds__(256) void build_bucket(const int2* __restrict__ ebuf,
                                                    const int* __restrict__ bbase,
                                                    int npb, int N,
                                                    int* __restrict__ row_ptr,
                                                    int* __restrict__ col,
                                                    int* __restrict__ edst) {
    __shared__ int degl[256];
    __shared__ int curl[256];
    const int b = blockIdx.x;
    const int t = threadIdx.x, lane = t & 63, wid = t >> 6;
    const int base = bbase[b];
    const int cnt = bbase[b + 1] - base;
    const int node0 = b * npb;
    for (int i = t; i < npb; i += 256) degl[i] = 0;
    __syncthreads();
    for (int i = t; i < cnt; i += 256) {
        int d = ebuf[base + i].y;
        atomicAdd(&degl[d - node0], 1);
    }
    __syncthreads();
    if (wid == 0) {
        int run = 0;
        for (int c = 0; c * 64 < npb; c++) {
            int idx = c * 64 + lane;
            int v = (idx < npb) ? degl[idx] : 0;
            int incl = v;
            #pragma unroll
            for (int o = 1; o < 64; o <<= 1) {
                int u = __shfl_up(incl, o, 64);
                if (lane >= o) incl += u;
            }
            int excl = incl - v + run;
            if (idx < npb) {
                curl[idx] = excl;
                int node = node0 + idx;
                if (node < N) row_ptr[node] = base + excl;
            }
            run += __shfl(incl, 63, 64);
        }
    }
    __syncthreads();
    for (int i = t; i < cnt; i += 256) {
        int2 ed = ebuf[base + i];
        int p = atomicAdd(&curl[ed.y - node0], 1);
        col[base + p] = ed.x;
        edst[base + p] = ed.y;
    }
}

// ---- per-(edge,head) softmax weights, fp16, one array per head -----------
__global__ __launch_bounds__(256) void edge_w(const int* __restrict__ col,
                                              const int* __restrict__ edst,
                                              const float4* __restrict__ as4,
                                              const float4* __restrict__ ad4,
                                              int E,
                                              unsigned short* __restrict__ q0,
                                              unsigned short* __restrict__ q1,
                                              unsigned short* __restrict__ q2,
                                              unsigned short* __restrict__ q3) {
    int i = blockIdx.x * 256 + threadIdx.x;
    if (i >= E) return;
    float4 a = as4[col[i]];
    float4 b = ad4[edst[i]];
    float ex = a.x + b.x, ey = a.y + b.y, ez = a.z + b.z, ew = a.w + b.w;
    ex = fmaxf(ex, 0.2f * ex); ey = fmaxf(ey, 0.2f * ey);
    ez = fmaxf(ez, 0.2f * ez); ew = fmaxf(ew, 0.2f * ew);
    __half hx = __float2half(__expf(ex));
    __half hy = __float2half(__expf(ey));
    __half hz = __float2half(__expf(ez));
    __half hw = __float2half(__expf(ew));
    q0[i] = *(unsigned short*)&hx;
    q1[i] = *(unsigned short*)&hy;
    q2[i] = *(unsigned short*)&hz;
    q3[i] = *(unsigned short*)&hw;
}

// ------------- gather aggregation: softmax-weighted sum per dst ------------
// block = 1 wave = 4 nodes x 16 lanes; parity p=b&3 selects head and its
// 3.2MB h quarter (L2-resident per XCD under round-robin dispatch).
// lane li gathers uint = feats 2li,2li+1 of h[p][node][32]. Weight =
// scalar fp16 from wq[p][E]. Plain loads everywhere (R12: NT removed).
__global__ __launch_bounds__(64) void aggregate(const unsigned short* __restrict__ hq,
                                                const unsigned short* __restrict__ wq,
                                                const float* __restrict__ a_s,
                                                const float* __restrict__ a_d,
                                                const int* __restrict__ row_ptr,
                                                const int* __restrict__ col,
                                                const float* __restrict__ bias,
                                                float* __restrict__ out,
                                                float* __restrict__ out2,
                                                int n, int E, int do_relu) {
    const int b = blockIdx.x;
    const int p = b & 3;                    // head (parity)
    const unsigned* __restrict__ hp =
        (const unsigned*)(hq + (size_t)p * n * 32);        // uint = 2 feats
    const unsigned short* __restrict__ wp = wq + (size_t)p * E;
    const int t = threadIdx.x;
    const int g  = t >> 4;                  // node within quad
    const int li = t & 15;                  // feature pair: feats 2li,2li+1
    const int node = (b >> 2) * 4 + g;
    const bool valid = node < n;
    const int nd = valid ? node : 0;

    // self loop
    float e = a_s[nd * NHEAD + p] + a_d[nd * NHEAD + p];
    e = fmaxf(e, 0.2f * e);
    float den = __expf(e);
    float num0, num1;
    {
        float2 hv = bf2f(hp[(size_t)nd * 16 + li]);
        num0 = den * hv.x;
        num1 = den * hv.y;
    }

    const int beg = row_ptr[nd];
    const int end = valid ? row_ptr[nd + 1] : beg;
    int j = beg;
    for (; j + 8 <= end; j += 8) {
        int s[8];
        #pragma unroll
        for (int u = 0; u < 8; u++) s[u] = col[j + u];
        unsigned v[8];
        #pragma unroll
        for (int u = 0; u < 8; u++) v[u] = hp[(size_t)s[u] * 16 + li];
        unsigned short hw[8];
        #pragma unroll
        for (int u = 0; u < 8; u++) hw[u] = wp[j + u];
        #pragma unroll
        for (int u = 0; u < 8; u++) {
            float wgt = __half2float(*(const __half*)&hw[u]);
            den += wgt;
            float2 f = bf2f(v[u]);
            num0 += wgt * f.x;
            num1 += wgt * f.y;
        }
    }
    for (; j < end; j++) {
        int s = col[j];
        unsigned short hw = wp[j];
        float wgt = __half2float(*(const __half*)&hw);
        den += wgt;
        float2 f = bf2f(hp[(size_t)s * 16 + li]);
        num0 += wgt * f.x;
        num1 += wgt * f.y;
    }

    if (valid) {
        float2 bv = ((const float2*)bias)[p * 16 + li];
        float rd = 1.0f / den;
        float o0 = num0 * rd + bv.x;
        float o1 = num1 * rd + bv.y;
        if (do_relu) { o0 = fmaxf(o0, 0.f); o1 = fmaxf(o1, 0.f); }
        ((float2*)out)[(size_t)node * 64 + p * 16 + li] = make_float2(o0, o1);
        if (out2)
            ((float2*)out2)[(size_t)node * 64 + p * 16 + li] = make_float2(o0, o1);
    }
}

// ------------------------------- launcher ----------------------------------
extern "C" void kernel_launch(void* const* d_in, const int* in_sizes, int n_in,
                              void* d_out, int out_size, void* d_ws, size_t ws_size,
                              hipStream_t stream) {
    const float* x        = (const float*)d_in[0];
    const int*   edge     = (const int*)d_in[1];
    const float* W1       = (const float*)d_in[2];
    const float* att_s1   = (const float*)d_in[3];
    const float* att_d1   = (const float*)d_in[4];
    const float* b1       = (const float*)d_in[5];
    const float* W2       = (const float*)d_in[6];
    const float* att_s2   = (const float*)d_in[7];
    const float* att_d2   = (const float*)d_in[8];
    const float* b2       = (const float*)d_in[9];
    float* out = (float*)d_out;

    const int N = in_sizes[0] / FDIM;         // 50000
    const int E = in_sizes[1] / 2;            // 1600000
    const int* src = edge;
    const int* dst = edge + E;

    const int npb = (N + NB - 1) / NB;        // 98
    const unsigned long long magic = ((1ull << 40) / (unsigned long long)npb) + 1;

    char* w = (char*)d_ws;
    size_t off = 0;
    auto alloc = [&](size_t bytes) { void* p = w + off; off = (off + bytes + 255) & ~(size_t)255; return p; };
    int*   row_ptr = (int*)alloc((size_t)(N + 1) * 4);
    int*   col     = (int*)alloc((size_t)E * 4);
    int*   edst    = (int*)alloc((size_t)E * 4);
    unsigned short* wqa = (unsigned short*)alloc((size_t)4 * E * 2);  // [4][E] fp16
    int*   bcnt    = (int*)alloc((size_t)NB * 4);
    int*   bbase   = (int*)alloc((size_t)(NB + 1) * 4);
    int*   bcursor = (int*)alloc((size_t)NB * 4);
    unsigned short* h = (unsigned short*)alloc((size_t)4 * N * 32 * 2); // [4][N][32] bf16
    float* hx      = (float*)alloc((size_t)N * FDIM * 4);   // layer-1 out; ebuf alias
    float* as1     = (float*)alloc((size_t)N * NHEAD * 4);
    float* ad1     = (float*)alloc((size_t)N * NHEAD * 4);
    float* as2     = (float*)alloc((size_t)N * NHEAD * 4);
    float* ad2     = (float*)alloc((size_t)N * NHEAD * 4);
    short* Bg1hi   = (short*)alloc((size_t)128 * 128 * 2);
    short* Bg1lo   = (short*)alloc((size_t)128 * 128 * 2);
    short* Bg2hi   = (short*)alloc((size_t)128 * 128 * 2);
    short* Bg2lo   = (short*)alloc((size_t)128 * 128 * 2);
    int2*  ebuf    = (int2*)hx;   // dead before aggregate-1 writes hx
    (void)ws_size;

    // ---- fused weight-prep + bucket histogram ----
    hipMemsetAsync(bcnt, 0, (size_t)NB * 4, stream);
    prep_hist<<<128 + 1024, 256, 0, stream>>>(W1, Bg1hi, Bg1lo, W2, Bg2hi, Bg2lo,
                                              dst, E, magic, bcnt);
    bucket_scan<<<1, 256, 0, stream>>>(bcnt, bbase, bcursor, row_ptr, N, E);
    partition<<<(E + 4095) / 4096, 256, 0, stream>>>(src, dst, E, magic, bcursor, ebuf);
    build_bucket<<<NB, 256, 0, stream>>>(ebuf, bbase, npb, N, row_ptr, col, edst);

    const int gblocks = (N + 63) / 64;
    const int eb = (E + 255) / 256;
    const int ablocks = ((N + 3) / 4) * 4;    // node quads x 4 head parities

    // ---- layer 1 ----
    gemm_mfma<<<gblocks, 256, 0, stream>>>(x, Bg1hi, Bg1lo, h,
                                           att_s1, att_d1, as1, ad1, N);
    edge_w<<<eb, 256, 0, stream>>>(col, edst, (const float4*)as1, (const float4*)ad1,
                                   E, wqa, wqa + (size_t)E, wqa + (size_t)2 * E,
                                   wqa + (size_t)3 * E);
    aggregate<<<ablocks, 64, 0, stream>>>(h, wqa, as1, ad1, row_ptr, col, b1,
                                          hx, nullptr, N, E, 1);

    // ---- layer 2 ----
    gemm_mfma<<<gblocks, 256, 0, stream>>>(hx, Bg2hi, Bg2lo, h,
                                           att_s2, att_d2, as2, ad2, N);
    edge_w<<<eb, 256, 0, stream>>>(col, edst, (const float4*)as2, (const float4*)ad2,
                                   E, wqa, wqa + (size_t)E, wqa + (size_t)2 * E,
                                   wqa + (size_t)3 * E);
    aggregate<<<ablocks, 64, 0, stream>>>(h, wqa, as2, ad2, row_ptr, col, b2,
                                          out, out + (size_t)N * FDIM, N, E, 0);
}

// Round 6
// 327.812 us; speedup vs baseline: 1.3008x; 1.0728x over previous
//
#include <hip/hip_runtime.h>
#include <hip/hip_bf16.h>
#include <hip/hip_fp16.h>

// GAT, 2 layers. N=50000, F=128, H=4, C=32, E=1.6M (+N self-loops).
// R7 (proven, 336us): h split into head-pair halves h0/h1 (6.4MB each);
// aggregate block parity selects the half -> per-XCD L2 set halves under
// round-robin dispatch. 1 wave = 2 nodes x 32 lanes, 8-chunk + scalar tail.
// R13: edge_w FUSED into aggregate. a_s/a_d stored planar [head][N];
// inner loop gathers as_h[s] (200KB plane, L2-resident) and computes
// wgt = exp(leaky(as+ad)) inline (ad hoisted per-wave). Removes: edge_w
// dispatches (x2), w0/w1 12.8MB write+read round trip, edst array (6.4MB
// scattered writes in build_bucket). VMEM/chunk unchanged (as gather
// replaces w load); VALU +3/edge (leaky+exp). R8-R12 ledger: aggregate
// core itself is at its empirical optimum in the R0/R7 shape - do not
// touch its loop structure. GEMM: split-bf16 MFMA (R5). CSR: R3.

#define FDIM 128
#define NHEAD 4
#define NB 512          // dst buckets for CSR build

typedef __attribute__((ext_vector_type(16))) float f32x16;
typedef __attribute__((ext_vector_type(8)))  short s16x8;

__device__ inline unsigned short f2bf(float f) {
    union { float f; unsigned u; } v; v.f = f;
    unsigned r = v.u + 0x7fff + ((v.u >> 16) & 1);   // RNE
    return (unsigned short)(r >> 16);
}
__device__ inline float2 bf2f(unsigned v) {
    union { unsigned u; float f; } a, b;
    a.u = v << 16;            // low half  = feature 2c
    b.u = v & 0xffff0000u;    // high half = feature 2c+1
    return make_float2(a.f, b.f);
}
__device__ inline void splitbf(float f, short* hi, short* lo) {
    unsigned u = __float_as_uint(f);
    float rem = f - __uint_as_float(u & 0xffff0000u);
    *hi = (short)(u >> 16);
    *lo = (short)(__float_as_uint(rem) >> 16);
}

// ---- fused: prep W1/W2 (transpose+split+swizzle) + bucket histogram ------
__global__ __launch_bounds__(256) void prep_hist(const float* __restrict__ W1,
                                                 short* __restrict__ B1hi,
                                                 short* __restrict__ B1lo,
                                                 const float* __restrict__ W2,
                                                 short* __restrict__ B2hi,
                                                 short* __restrict__ B2lo,
                                                 const int* __restrict__ dst, int E,
                                                 unsigned long long magic,
                                                 int* __restrict__ bcnt) {
    __shared__ int sh[NB];
    const int t = threadIdx.x;
    const int b = blockIdx.x;
    if (b < 128) {
        const float* W = (b < 64) ? W1 : W2;
        short* Bhi = (b < 64) ? B1hi : B2hi;
        short* Blo = (b < 64) ? B1lo : B2lo;
        int e = (b & 63) * 256 + t;   // e = k*128 + n
        int k = e >> 7, n = e & 127;
        short hi, lo;
        splitbf(W[e], &hi, &lo);
        int idx = n * 128 + (((k >> 3) ^ (n & 15)) << 3) + (k & 7);
        Bhi[idx] = hi;
        Blo[idx] = lo;
        return;
    }
    for (int i = t; i < NB; i += 256) sh[i] = 0;
    __syncthreads();
    const int stride = (gridDim.x - 128) * 256;
    for (int i = (b - 128) * 256 + t; i < E; i += stride) {
        int bk = (int)(((unsigned long long)(unsigned)dst[i] * magic) >> 40);
        atomicAdd(&sh[bk], 1);
    }
    __syncthreads();
    for (int i = t; i < NB; i += 256)
        if (sh[i]) atomicAdd(&bcnt[i], sh[i]);
}

// ---- MFMA GEMM: H0/H1[M][64](bf16) = A[M][128](f32) @ W; fused a_s/a_d ---
// a_s/a_d written PLANAR: a_s[q*M + row]  (R13: cheap per-head gather)
__global__ __launch_bounds__(256) void gemm_mfma(const float* __restrict__ A,
                                                 const short* __restrict__ Bghi,
                                                 const short* __restrict__ Bglo,
                                                 unsigned short* __restrict__ H0,
                                                 unsigned short* __restrict__ H1,
                                                 const float* __restrict__ att_s,
                                                 const float* __restrict__ att_d,
                                                 float* __restrict__ a_s,
                                                 float* __restrict__ a_d, int M) {
    __shared__ short Bsm[2][16384];   // 64 KB: [hi/lo][n*128 + k']
    __shared__ float attsm[256];      // att_s[128], att_d[128]
    const int t = threadIdx.x;
    const int bm = blockIdx.x * 64;

    if (t < 128) attsm[t] = att_s[t];
    else         attsm[t] = att_d[t - 128];

    {   // stage B (pre-swizzled; verbatim 32KB+32KB copy)
        const uint4* ghi = (const uint4*)Bghi;
        const uint4* glo = (const uint4*)Bglo;
        uint4* shi = (uint4*)&Bsm[0][0];
        uint4* slo = (uint4*)&Bsm[1][0];
        #pragma unroll
        for (int i = 0; i < 8; i++) {
            shi[t + i * 256] = ghi[t + i * 256];
            slo[t + i * 256] = glo[t + i * 256];
        }
    }

    const int lane = t & 63;
    const int w = t >> 6;
    const int wr = w >> 1, wc = w & 1;     // wave tile: rows wr*32, cols wc*32
    const int m  = lane & 31, h2 = lane >> 5;
    const int grow = bm + wr * 32 + m;

    // A fragments: 8 k-chunks of 16; lane holds k = 16c + 8*h2 + j (j=0..7)
    s16x8 ahi[8], alo[8];
    {
        const bool ok = grow < M;
        const float* ap = A + (size_t)grow * 128 + 8 * h2;
        #pragma unroll
        for (int c = 0; c < 8; c++) {
            float ff[8];
            if (ok) {
                float4 f0 = *(const float4*)(ap + c * 16);
                float4 f1 = *(const float4*)(ap + c * 16 + 4);
                ff[0]=f0.x; ff[1]=f0.y; ff[2]=f0.z; ff[3]=f0.w;
                ff[4]=f1.x; ff[5]=f1.y; ff[6]=f1.z; ff[7]=f1.w;
            } else {
                #pragma unroll
                for (int j = 0; j < 8; j++) ff[j] = 0.f;
            }
            #pragma unroll
            for (int j = 0; j < 8; j++) {
                short hi, lo;
                splitbf(ff[j], &hi, &lo);
                ahi[c][j] = hi;
                alo[c][j] = lo;
            }
        }
    }
    __syncthreads();

    f32x16 acc[2];
    #pragma unroll
    for (int i = 0; i < 16; i++) { acc[0][i] = 0.f; acc[1][i] = 0.f; }

    #pragma unroll
    for (int ni = 0; ni < 2; ni++) {
        const int n = ni * 64 + wc * 32 + m;     // B col for this lane
        const int nbase = n * 128;
        #pragma unroll
        for (int c = 0; c < 8; c++) {
            int chunk8 = 2 * c + h2;
            int koff = ((chunk8 ^ (n & 15)) << 3);
            s16x8 bhi = *(const s16x8*)&Bsm[0][nbase + koff];
            s16x8 blo = *(const s16x8*)&Bsm[1][nbase + koff];
            acc[ni] = __builtin_amdgcn_mfma_f32_32x32x16_bf16(ahi[c], bhi, acc[ni], 0, 0, 0);
            acc[ni] = __builtin_amdgcn_mfma_f32_32x32x16_bf16(alo[c], bhi, acc[ni], 0, 0, 0);
            acc[ni] = __builtin_amdgcn_mfma_f32_32x32x16_bf16(ahi[c], blo, acc[ni], 0, 0, 0);
        }
    }

    __syncthreads();   // all waves done reading Bsm; reuse as htile
    unsigned short* htile = (unsigned short*)&Bsm[0][0];   // [64][128] bf16
    #pragma unroll
    for (int ni = 0; ni < 2; ni++) {
        const int colg = ni * 64 + wc * 32 + m;
        #pragma unroll
        for (int r = 0; r < 16; r++) {
            int row = wr * 32 + (r & 3) + 8 * (r >> 2) + 4 * h2;  // C/D m74/m101
            htile[row * 128 + colg] = (short)f2bf(acc[ni][r]);
        }
    }
    __syncthreads();

    // copy h tile out (split by head pair) + logits: thread = (row r, head q)
    {
        const int r = t >> 2, q = t & 3;
        const int growr = bm + r;
        if (growr < M) {
            uint4 v0 = *(uint4*)&htile[r * 128 + q * 32];
            uint4 v1 = *(uint4*)&htile[r * 128 + q * 32 + 8];
            uint4 v2 = *(uint4*)&htile[r * 128 + q * 32 + 16];
            uint4 v3 = *(uint4*)&htile[r * 128 + q * 32 + 24];
            unsigned short* Hp = (q < 2) ? H0 : H1;
            uint4* hg = (uint4*)(Hp + (size_t)growr * 64);
            const int qq = q & 1;
            hg[qq * 4 + 0] = v0; hg[qq * 4 + 1] = v1;
            hg[qq * 4 + 2] = v2; hg[qq * 4 + 3] = v3;
            unsigned uu[16] = {v0.x, v0.y, v0.z, v0.w, v1.x, v1.y, v1.z, v1.w,
                               v2.x, v2.y, v2.z, v2.w, v3.x, v3.y, v3.z, v3.w};
            float ps = 0.f, pd = 0.f;
            #pragma unroll
            for (int i = 0; i < 16; i++) {
                float2 f = bf2f(uu[i]);
                ps += f.x * attsm[q * 32 + 2 * i]       + f.y * attsm[q * 32 + 2 * i + 1];
                pd += f.x * attsm[128 + q * 32 + 2 * i] + f.y * attsm[128 + q * 32 + 2 * i + 1];
            }
            a_s[(size_t)q * M + growr] = ps;     // planar [head][M]
            a_d[(size_t)q * M + growr] = pd;
        }
    }
}

// ------------------------------ CSR build ---------------------------------
__global__ __launch_bounds__(256) void bucket_scan(const int* __restrict__ bcnt,
                                                   int* __restrict__ bbase,
                                                   int* __restrict__ bcursor,
                                                   int* __restrict__ row_ptr,
                                                   int N, int E) {
    __shared__ int wsum[4];
    const int t = threadIdx.x, lane = t & 63, wid = t >> 6;
    int v0 = bcnt[2 * t], v1 = bcnt[2 * t + 1];
    int s = v0 + v1, incl = s;
    #pragma unroll
    for (int o = 1; o < 64; o <<= 1) {
        int u = __shfl_up(incl, o, 64);
        if (lane >= o) incl += u;
    }
    if (lane == 63) wsum[wid] = incl;
    __syncthreads();
    if (t == 0) {
        int a = 0;
        #pragma unroll
        for (int i = 0; i < 4; i++) { int x = wsum[i]; wsum[i] = a; a += x; }
    }
    __syncthreads();
    int excl = wsum[wid] + incl - s;
    bbase[2 * t] = excl;          bcursor[2 * t] = excl;
    bbase[2 * t + 1] = excl + v0; bcursor[2 * t + 1] = excl + v0;
    if (t == 0) { bbase[NB] = E; row_ptr[N] = E; }
}

__global__ __launch_bounds__(256) void partition(const int* __restrict__ src,
                                                 const int* __restrict__ dst, int E,
                                                 unsigned long long magic,
                                                 int* __restrict__ bcursor,
                                                 int2* __restrict__ ebuf) {
    __shared__ int shc[NB];    // per-bucket count in this block
    __shared__ int shb[NB];    // reserved global base
    __shared__ int shcur[NB];  // local cursor
    const int t = threadIdx.x;
    for (int i = t; i < NB; i += 256) shc[i] = 0;
    __syncthreads();
    const int e0 = blockIdx.x * 4096;
    int myb[16], mys[16], myd[16];
    #pragma unroll
    for (int u = 0; u < 16; u++) {
        int i = e0 + u * 256 + t;
        if (i < E) {
            mys[u] = src[i];
            myd[u] = dst[i];
            int b = (int)(((unsigned long long)(unsigned)myd[u] * magic) >> 40);
            myb[u] = b;
            atomicAdd(&shc[b], 1);
        } else myb[u] = -1;
    }
    __syncthreads();
    for (int i = t; i < NB; i += 256) {
        int c = shc[i];
        shcur[i] = 0;
        if (c) shb[i] = atomicAdd(&bcursor[i], c);
    }
    __syncthreads();
    #pragma unroll
    for (int u = 0; u < 16; u++) {
        if (myb[u] >= 0) {
            int o = atomicAdd(&shcur[myb[u]], 1);
            ebuf[shb[myb[u]] + o] = make_int2(mys[u], myd[u]);
        }
    }
}

__global__ __launch_bounds__(256) void build_bucket(const int2* __restrict__ ebuf,
                                                    const int* __restrict__ bbase,
                                                    int npb, int N,
                                                    int* __restrict__ row_ptr,
                                                    int* __restrict__ col) {
    __shared__ int degl[256];
    __shared__ int curl[256];
    const int b = blockIdx.x;
    const int t = threadIdx.x, lane = t & 63, wid = t >> 6;
    const int base = bbase[b];
    const int cnt = bbase[b + 1] - base;
    const int node0 = b * npb;
    for (int i = t; i < npb; i += 256) degl[i] = 0;
    __syncthreads();
    for (int i = t; i < cnt; i += 256) {
        int d = ebuf[base + i].y;
        atomicAdd(&degl[d - node0], 1);
    }
    __syncthreads();
    if (wid == 0) {
        int run = 0;
        for (int c = 0; c * 64 < npb; c++) {
            int idx = c * 64 + lane;
            int v = (idx < npb) ? degl[idx] : 0;
            int incl = v;
            #pragma unroll
            for (int o = 1; o < 64; o <<= 1) {
                int u = __shfl_up(incl, o, 64);
                if (lane >= o) incl += u;
            }
            int excl = incl - v + run;
            if (idx < npb) {
                curl[idx] = excl;
                int node = node0 + idx;
                if (node < N) row_ptr[node] = base + excl;
            }
            run += __shfl(incl, 63, 64);
        }
    }
    __syncthreads();
    for (int i = t; i < cnt; i += 256) {
        int2 ed = ebuf[base + i];
        int p = atomicAdd(&curl[ed.y - node0], 1);
        col[base + p] = ed.x;
    }
}

// ------------- gather aggregation: fused softmax-weighted sum per dst ------
// block = 1 wave = 2 nodes x 32 lanes; parity b&1 selects head pair and its
// 6.4MB h-half -> per-XCD L2 working set halves under round-robin dispatch.
// lane li handles features 2li,2li+1 of the pair's 64-feature half.
// R13: weight computed inline: wgt = exp(leaky(a_s[hd][s] + a_d[hd][node]))
// (a_s plane 200KB, L2-resident; adv hoisted). No edge_w kernel, no w array.
__global__ __launch_bounds__(64) void aggregate(const unsigned* __restrict__ h0,
                                                const unsigned* __restrict__ h1,
                                                const float* __restrict__ a_s,
                                                const float* __restrict__ a_d,
                                                const int* __restrict__ row_ptr,
                                                const int* __restrict__ col,
                                                const float* __restrict__ bias,
                                                float* __restrict__ out,
                                                float* __restrict__ out2,
                                                int n, int do_relu) {
    const int b = blockIdx.x;
    const int p = b & 1;                    // head pair
    const unsigned* __restrict__ hp = p ? h1 : h0;
    const int t = threadIdx.x;
    const int g = t >> 5;                   // node within pair
    const int li = t & 31;
    const int node = (b >> 1) * 2 + g;
    if (node >= n) return;
    const int hd = p * 2 + (li >> 4);
    const float* __restrict__ as_h = a_s + (size_t)hd * n;   // planar plane
    const float adv = a_d[(size_t)hd * n + node];            // hoisted

    // self loop
    float e = as_h[node] + adv;
    e = fmaxf(e, 0.2f * e);
    float den = __expf(e);
    float2 hv = bf2f(hp[(size_t)node * 32 + li]);
    float num0 = den * hv.x, num1 = den * hv.y;

    const int beg = row_ptr[node], end = row_ptr[node + 1];
    int j = beg;
    for (; j + 8 <= end; j += 8) {
        int s[8];
        #pragma unroll
        for (int u = 0; u < 8; u++) s[u] = col[j + u];
        unsigned v[8];
        #pragma unroll
        for (int u = 0; u < 8; u++) v[u] = hp[(size_t)s[u] * 32 + li];
        float av[8];
        #pragma unroll
        for (int u = 0; u < 8; u++) av[u] = as_h[s[u]];
        #pragma unroll
        for (int u = 0; u < 8; u++) {
            float ee = av[u] + adv;
            ee = fmaxf(ee, 0.2f * ee);
            float wgt = __expf(ee);
            den += wgt;
            float2 f = bf2f(v[u]);
            num0 += wgt * f.x;
            num1 += wgt * f.y;
        }
    }
    for (; j < end; j++) {
        int s = col[j];
        float ee = as_h[s] + adv;
        ee = fmaxf(ee, 0.2f * ee);
        float wgt = __expf(ee);
        den += wgt;
        float2 f = bf2f(hp[(size_t)s * 32 + li]);
        num0 += wgt * f.x;
        num1 += wgt * f.y;
    }
    float2 bv = ((const float2*)bias)[p * 32 + li];
    float rd = 1.0f / den;
    float o0 = num0 * rd + bv.x;
    float o1 = num1 * rd + bv.y;
    if (do_relu) { o0 = fmaxf(o0, 0.f); o1 = fmaxf(o1, 0.f); }
    ((float2*)out)[(size_t)node * 64 + p * 32 + li] = make_float2(o0, o1);
    if (out2) ((float2*)out2)[(size_t)node * 64 + p * 32 + li] = make_float2(o0, o1);
}

// ------------------------------- launcher ----------------------------------
extern "C" void kernel_launch(void* const* d_in, const int* in_sizes, int n_in,
                              void* d_out, int out_size, void* d_ws, size_t ws_size,
                              hipStream_t stream) {
    const float* x        = (const float*)d_in[0];
    const int*   edge     = (const int*)d_in[1];
    const float* W1       = (const float*)d_in[2];
    const float* att_s1   = (const float*)d_in[3];
    const float* att_d1   = (const float*)d_in[4];
    const float* b1       = (const float*)d_in[5];
    const float* W2       = (const float*)d_in[6];
    const float* att_s2   = (const float*)d_in[7];
    const float* att_d2   = (const float*)d_in[8];
    const float* b2       = (const float*)d_in[9];
    float* out = (float*)d_out;

    const int N = in_sizes[0] / FDIM;         // 50000
    const int E = in_sizes[1] / 2;            // 1600000
    const int* src = edge;
    const int* dst = edge + E;

    const int npb = (N + NB - 1) / NB;        // 98
    const unsigned long long magic = ((1ull << 40) / (unsigned long long)npb) + 1;

    char* w = (char*)d_ws;
    size_t off = 0;
    auto alloc = [&](size_t bytes) { void* p = w + off; off = (off + bytes + 255) & ~(size_t)255; return p; };
    int*   row_ptr = (int*)alloc((size_t)(N + 1) * 4);
    int*   col     = (int*)alloc((size_t)E * 4);
    int*   bcnt    = (int*)alloc((size_t)NB * 4);
    int*   bbase   = (int*)alloc((size_t)(NB + 1) * 4);
    int*   bcursor = (int*)alloc((size_t)NB * 4);
    unsigned short* h0 = (unsigned short*)alloc((size_t)N * 64 * 2);  // heads 0,1 bf16
    unsigned short* h1 = (unsigned short*)alloc((size_t)N * 64 * 2);  // heads 2,3 bf16
    float* hx      = (float*)alloc((size_t)N * FDIM * 4);   // layer-1 out; ebuf alias
    float* as1     = (float*)alloc((size_t)NHEAD * N * 4);  // planar [4][N]
    float* ad1     = (float*)alloc((size_t)NHEAD * N * 4);
    float* as2     = (float*)alloc((size_t)NHEAD * N * 4);
    float* ad2     = (float*)alloc((size_t)NHEAD * N * 4);
    short* Bg1hi   = (short*)alloc((size_t)128 * 128 * 2);
    short* Bg1lo   = (short*)alloc((size_t)128 * 128 * 2);
    short* Bg2hi   = (short*)alloc((size_t)128 * 128 * 2);
    short* Bg2lo   = (short*)alloc((size_t)128 * 128 * 2);
    int2*  ebuf    = (int2*)hx;   // dead before aggregate-1 writes hx
    (void)ws_size;

    // ---- fused weight-prep + bucket histogram ----
    hipMemsetAsync(bcnt, 0, (size_t)NB * 4, stream);
    prep_hist<<<128 + 1024, 256, 0, stream>>>(W1, Bg1hi, Bg1lo, W2, Bg2hi, Bg2lo,
                                              dst, E, magic, bcnt);
    bucket_scan<<<1, 256, 0, stream>>>(bcnt, bbase, bcursor, row_ptr, N, E);
    partition<<<(E + 4095) / 4096, 256, 0, stream>>>(src, dst, E, magic, bcursor, ebuf);
    build_bucket<<<NB, 256, 0, stream>>>(ebuf, bbase, npb, N, row_ptr, col);

    const int gblocks = (N + 63) / 64;
    const int ablocks = ((N + 1) / 2) * 2;    // node pairs x 2 parities

    // ---- layer 1 ----
    gemm_mfma<<<gblocks, 256, 0, stream>>>(x, Bg1hi, Bg1lo, h0, h1,
                                           att_s1, att_d1, as1, ad1, N);
    aggregate<<<ablocks, 64, 0, stream>>>((const unsigned*)h0, (const unsigned*)h1,
                                          as1, ad1, row_ptr, col, b1,
                                          hx, nullptr, N, 1);

    // ---- layer 2 ----
    gemm_mfma<<<gblocks, 256, 0, stream>>>(hx, Bg2hi, Bg2lo, h0, h1,
                                           att_s2, att_d2, as2, ad2, N);
    aggregate<<<ablocks, 64, 0, stream>>>((const unsigned*)h0, (const unsigned*)h1,
                                          as2, ad2, row_ptr, col, b2,
                                          out, out + (size_t)N * FDIM, N, 0);
}